// Round 1
// baseline (746.544 us; speedup 1.0000x reference)
//
#include <hip/hip_runtime.h>

#define HW 4096

// ---------------------------------------------------------------------------
// Kernel 1: 1x1-conv projection.  dst[b][o][n] = sum_c W[o][c] * X[b][c][n] + bias[o]
// z==1 (Fp path) additionally L2-normalizes over o (128 channels).
// q (z==0) is intentionally NOT normalized: argmax over m is invariant to a
// positive per-row scale of q, and skipping the divide removes a rounding step.
// ---------------------------------------------------------------------------
__global__ __launch_bounds__(256) void proj_kernel(
    const float* __restrict__ Fq, const float* __restrict__ Fp,
    const float* __restrict__ Wm, const float* __restrict__ bias,
    float* __restrict__ Qo, float* __restrict__ Po)
{
    __shared__ float Xs[64][64];   // 16 KB: one 64c x 64n chunk
    __shared__ float sq[4][64];    // norm partials

    const int tid = threadIdx.x;
    const int z  = blockIdx.z;                 // 0: q from Fq, 1: p from Fp
    const float* __restrict__ X = z ? Fp : Fq;
    float* __restrict__ dst     = z ? Po : Qo;

    const int b  = blockIdx.y;
    const int n0 = blockIdx.x * 64;
    const int n  = tid & 63;
    // wave-uniform o-group (forces scalar loads of W)
    const int og = __builtin_amdgcn_readfirstlane(tid >> 6);

    float acc[32];
    #pragma unroll
    for (int j = 0; j < 32; ++j) acc[j] = 0.f;

    for (int cc = 0; cc < 4; ++cc) {
        // stage chunk: rows c = cc*64 .. cc*64+63, cols n0..n0+63 (coalesced)
        #pragma unroll
        for (int i = 0; i < 16; ++i) {
            int idx = tid + i * 256;
            int r = idx >> 6, nn = idx & 63;
            Xs[r][nn] = X[(size_t)(b * 256 + cc * 64 + r) * HW + n0 + nn];
        }
        __syncthreads();
        for (int r = 0; r < 64; ++r) {
            float x = Xs[r][n];
            int c = cc * 64 + r;
            #pragma unroll
            for (int j = 0; j < 32; ++j)
                acc[j] += Wm[(og * 32 + j) * 256 + c] * x;   // scalar (SGPR) W loads
        }
        __syncthreads();
    }

    #pragma unroll
    for (int j = 0; j < 32; ++j) acc[j] += bias[og * 32 + j];

    if (z) {  // normalize over the 128 output channels
        float p = 0.f;
        #pragma unroll
        for (int j = 0; j < 32; ++j) p += acc[j] * acc[j];
        sq[og][n] = p;
        __syncthreads();
        float tot = sq[0][n] + sq[1][n] + sq[2][n] + sq[3][n];
        float s = 1.0f / sqrtf(tot);
        #pragma unroll
        for (int j = 0; j < 32; ++j) acc[j] *= s;
    }

    #pragma unroll
    for (int j = 0; j < 32; ++j)
        dst[(size_t)(b * 128 + og * 32 + j) * HW + n0 + n] = acc[j];
}

// ---------------------------------------------------------------------------
// Kernel 2: fused sim + argmax.  For each (b, n): idx = argmax_m  q_n . p_hat_m
// fp32 throughout, sequential c-order accumulation (error ~1e-7 << typical
// top1-top2 gap ~9e-3, so argmax matches the np fp32 reference).
// Tie-break: smallest m (np.argmax first-occurrence semantics).
// ---------------------------------------------------------------------------
__global__ __launch_bounds__(256) void simargmax_kernel(
    const float* __restrict__ Q, const float* __restrict__ P,
    int* __restrict__ IDX)
{
    __shared__ float Qs[128][64];   // 32 KB, resident for the whole block
    __shared__ float Ps[64][64];    // 16 KB, c-chunked per m-tile
    __shared__ float redv[64][17];  // +1 pad: conflict-free row reduce
    __shared__ int   redi[64][17];

    const int tid = threadIdx.x;
    const int b  = blockIdx.y;
    const int n0 = blockIdx.x * 64;
    const int tx = tid & 15;   // m sub-tile (4 m's)
    const int ty = tid >> 4;   // n sub-tile (4 n's)

    // load Q tile once: [128 c][64 n]
    for (int i = tid; i < 128 * 64; i += 256) {
        int o = i >> 6, nn = i & 63;
        Qs[o][nn] = Q[(size_t)(b * 128 + o) * HW + n0 + nn];
    }

    float bestv[4];
    int   besti[4];
    #pragma unroll
    for (int i = 0; i < 4; ++i) { bestv[i] = -1e30f; besti[i] = 0; }

    for (int mt = 0; mt < 64; ++mt) {
        const int m0 = mt * 64;
        float acc[4][4];
        #pragma unroll
        for (int i = 0; i < 4; ++i)
            #pragma unroll
            for (int j = 0; j < 4; ++j) acc[i][j] = 0.f;

        for (int h = 0; h < 2; ++h) {
            __syncthreads();   // covers initial Q load + prior tile's Ps reads
            for (int i = tid; i < 64 * 64; i += 256) {
                int o = i >> 6, mm = i & 63;
                Ps[o][mm] = P[(size_t)(b * 128 + h * 64 + o) * HW + m0 + mm];
            }
            __syncthreads();
            #pragma unroll 4
            for (int c = 0; c < 64; ++c) {
                float4 qv = *(const float4*)&Qs[h * 64 + c][ty * 4];
                float4 pv = *(const float4*)&Ps[c][tx * 4];
                float qa[4] = {qv.x, qv.y, qv.z, qv.w};
                float pa[4] = {pv.x, pv.y, pv.z, pv.w};
                #pragma unroll
                for (int i = 0; i < 4; ++i)
                    #pragma unroll
                    for (int j = 0; j < 4; ++j)
                        acc[i][j] += qa[i] * pa[j];
            }
        }

        // running argmax; strict > keeps earliest m within this thread's
        // (globally ascending) m subsequence
        #pragma unroll
        for (int i = 0; i < 4; ++i)
            #pragma unroll
            for (int j = 0; j < 4; ++j)
                if (acc[i][j] > bestv[i]) { bestv[i] = acc[i][j]; besti[i] = m0 + tx * 4 + j; }
    }

    __syncthreads();
    #pragma unroll
    for (int i = 0; i < 4; ++i) {
        redv[ty * 4 + i][tx] = bestv[i];
        redi[ty * 4 + i][tx] = besti[i];
    }
    __syncthreads();
    if (tid < 64) {
        float bv = redv[tid][0];
        int   bi = redi[tid][0];
        #pragma unroll
        for (int j = 1; j < 16; ++j) {
            float v = redv[tid][j];
            int  ii = redi[tid][j];
            if (v > bv || (v == bv && ii < bi)) { bv = v; bi = ii; }
        }
        IDX[b * HW + n0 + tid] = bi;
    }
}

// ---------------------------------------------------------------------------
// Kernel 3: gather.  out[b][c][n] = Fp[b][c][ IDX[b][n] ]
// ---------------------------------------------------------------------------
__global__ __launch_bounds__(256) void gather_kernel(
    const float* __restrict__ Fp, const int* __restrict__ IDX,
    float* __restrict__ out)
{
    const int i = blockIdx.x * 256 + threadIdx.x;   // 4*256*4096 total
    const int n = i & 4095;
    const int c = (i >> 12) & 255;
    const int b = i >> 20;
    const int idx = IDX[(b << 12) + n];
    out[i] = Fp[(size_t)((b << 8) + c) * HW + idx];
}

extern "C" void kernel_launch(void* const* d_in, const int* in_sizes, int n_in,
                              void* d_out, int out_size, void* d_ws, size_t ws_size,
                              hipStream_t stream) {
    const float* Fq   = (const float*)d_in[0];
    const float* Fp   = (const float*)d_in[1];
    const float* Wm   = (const float*)d_in[2];
    const float* bias = (const float*)d_in[3];
    float* out = (float*)d_out;

    // workspace: Q [4*128*4096] f32 (8 MB) | P [4*128*4096] f32 (8 MB) | IDX [4*4096] i32
    float* Q   = (float*)d_ws;
    float* P   = Q + (size_t)4 * 128 * HW;
    int*   IDX = (int*)(P + (size_t)4 * 128 * HW);

    proj_kernel<<<dim3(64, 4, 2), 256, 0, stream>>>(Fq, Fp, Wm, bias, Q, P);
    simargmax_kernel<<<dim3(64, 4), 256, 0, stream>>>(Q, P, IDX);
    gather_kernel<<<16384, 256, 0, stream>>>(Fp, IDX, out);
}

// Round 2
// 464.274 us; speedup vs baseline: 1.6080x; 1.6080x over previous
//
#include <hip/hip_runtime.h>

#define HW 4096

// ---------------------------------------------------------------------------
// Kernel 1: 1x1-conv projection.  dst[b][o][n] = sum_c W[o][c] * X[b][c][n] + bias[o]
// z==1 (Fp path) additionally L2-normalizes over o (128 channels).
// q (z==0) is intentionally NOT normalized: argmax over m is invariant to a
// positive per-row scale of q.
// ---------------------------------------------------------------------------
__global__ __launch_bounds__(256) void proj_kernel(
    const float* __restrict__ Fq, const float* __restrict__ Fp,
    const float* __restrict__ Wm, const float* __restrict__ bias,
    float* __restrict__ Qo, float* __restrict__ Po)
{
    __shared__ float Xs[64][64];   // 16 KB: one 64c x 64n chunk
    __shared__ float sq[4][64];    // norm partials

    const int tid = threadIdx.x;
    const int z  = blockIdx.z;                 // 0: q from Fq, 1: p from Fp
    const float* __restrict__ X = z ? Fp : Fq;
    float* __restrict__ dst     = z ? Po : Qo;

    const int b  = blockIdx.y;
    const int n0 = blockIdx.x * 64;
    const int n  = tid & 63;
    // wave-uniform o-group (forces scalar loads of W)
    const int og = __builtin_amdgcn_readfirstlane(tid >> 6);

    float acc[32];
    #pragma unroll
    for (int j = 0; j < 32; ++j) acc[j] = 0.f;

    for (int cc = 0; cc < 4; ++cc) {
        #pragma unroll
        for (int i = 0; i < 16; ++i) {
            int idx = tid + i * 256;
            int r = idx >> 6, nn = idx & 63;
            Xs[r][nn] = X[(size_t)(b * 256 + cc * 64 + r) * HW + n0 + nn];
        }
        __syncthreads();
        for (int r = 0; r < 64; ++r) {
            float x = Xs[r][n];
            int c = cc * 64 + r;
            #pragma unroll
            for (int j = 0; j < 32; ++j)
                acc[j] += Wm[(og * 32 + j) * 256 + c] * x;   // scalar (SGPR) W loads
        }
        __syncthreads();
    }

    #pragma unroll
    for (int j = 0; j < 32; ++j) acc[j] += bias[og * 32 + j];

    if (z) {  // normalize over the 128 output channels
        float p = 0.f;
        #pragma unroll
        for (int j = 0; j < 32; ++j) p += acc[j] * acc[j];
        sq[og][n] = p;
        __syncthreads();
        float tot = sq[0][n] + sq[1][n] + sq[2][n] + sq[3][n];
        float s = 1.0f / sqrtf(tot);
        #pragma unroll
        for (int j = 0; j < 32; ++j) acc[j] *= s;
    }

    #pragma unroll
    for (int j = 0; j < 32; ++j)
        dst[(size_t)(b * 128 + og * 32 + j) * HW + n0 + n] = acc[j];
}

// ---------------------------------------------------------------------------
// Kernel 2: fused sim + partial argmax.
// Block tile: 256 n x 128 m, per-thread register tile 16n x 8m
//   (128 FMA per 96 B LDS read -> LDS:VALU balanced, vs 16:32B before).
// Sub-tiled fragment layout keeps LDS reads contiguous across lanes:
//   n_i = n0 + (i>>2)*64 + ty*4 + (i&3),  m_j = m0 + (j>>2)*64 + tx*4 + (j&3)
// m-dimension split 8x across blockIdx.z for occupancy (512 blocks, 2/CU).
// fp32 throughout; per-thread m-sequence is ascending so strict > keeps
// np.argmax first-occurrence semantics; cross-lane merges tie-break on index.
// ---------------------------------------------------------------------------
__global__ __launch_bounds__(256, 2) void simargmax_kernel(
    const float* __restrict__ Q, const float* __restrict__ P,
    float* __restrict__ Vpart, int* __restrict__ Ipart)
{
    __shared__ float Qs[16][256];   // 16 KB: c-chunk x n-tile
    __shared__ float Ps[16][128];   // 8 KB:  c-chunk x m-tile

    const int tid = threadIdx.x;
    const int b  = blockIdx.y;
    const int n0 = blockIdx.x * 256;
    const int s  = blockIdx.z;      // m-split: covers m in [s*512, s*512+512)
    const int tx = tid & 15;
    const int ty = tid >> 4;

    float bestv[16];
    int   besti[16];
    #pragma unroll
    for (int i = 0; i < 16; ++i) { bestv[i] = -1e30f; besti[i] = 0; }

    const size_t qbase = (size_t)b * 128 * HW + n0;
    const size_t pbase = (size_t)b * 128 * HW + s * 512;

    for (int mt = 0; mt < 4; ++mt) {
        const int m0 = s * 512 + mt * 128;

        float acc[16][8];
        #pragma unroll
        for (int i = 0; i < 16; ++i)
            #pragma unroll
            for (int j = 0; j < 8; ++j) acc[i][j] = 0.f;

        for (int cc = 0; cc < 8; ++cc) {
            __syncthreads();   // protect prior chunk's reads
            // stage Q chunk: rows c = cc*16..+15, cols n0..n0+255 (float4)
            #pragma unroll
            for (int it = 0; it < 4; ++it) {
                int flat = it * 256 + tid;           // 1024 float4s
                int r = flat >> 6, c4 = flat & 63;
                *(float4*)&Qs[r][c4 * 4] =
                    *(const float4*)&Q[qbase + (size_t)(cc * 16 + r) * HW + c4 * 4];
            }
            // stage P chunk: rows c = cc*16..+15, cols m0..m0+127
            #pragma unroll
            for (int it = 0; it < 2; ++it) {
                int flat = it * 256 + tid;           // 512 float4s
                int r = flat >> 5, c4 = flat & 31;
                *(float4*)&Ps[r][c4 * 4] =
                    *(const float4*)&P[pbase + (size_t)(cc * 16 + r) * HW + mt * 128 + c4 * 4];
            }
            __syncthreads();

            #pragma unroll
            for (int c = 0; c < 16; ++c) {
                float qa[16], pa[8];
                *(float4*)&qa[0]  = *(const float4*)&Qs[c][      ty * 4];
                *(float4*)&qa[4]  = *(const float4*)&Qs[c][ 64 + ty * 4];
                *(float4*)&qa[8]  = *(const float4*)&Qs[c][128 + ty * 4];
                *(float4*)&qa[12] = *(const float4*)&Qs[c][192 + ty * 4];
                *(float4*)&pa[0]  = *(const float4*)&Ps[c][      tx * 4];
                *(float4*)&pa[4]  = *(const float4*)&Ps[c][ 64 + tx * 4];
                #pragma unroll
                for (int i = 0; i < 16; ++i)
                    #pragma unroll
                    for (int j = 0; j < 8; ++j)
                        acc[i][j] += qa[i] * pa[j];
            }
        }

        // running argmax (thread's m sequence ascending in j)
        #pragma unroll
        for (int i = 0; i < 16; ++i)
            #pragma unroll
            for (int j = 0; j < 8; ++j) {
                int m = m0 + (j >> 2) * 64 + tx * 4 + (j & 3);
                if (acc[i][j] > bestv[i]) { bestv[i] = acc[i][j]; besti[i] = m; }
            }
    }

    // cross-tx reduce: same-ty threads are lanes differing in bits 0..3
    #pragma unroll
    for (int i = 0; i < 16; ++i) {
        float v = bestv[i];
        int   ix = besti[i];
        #pragma unroll
        for (int d = 1; d < 16; d <<= 1) {
            float ov = __shfl_xor(v, d, 64);
            int   oi = __shfl_xor(ix, d, 64);
            if (ov > v || (ov == v && oi < ix)) { v = ov; ix = oi; }
        }
        if (tx == 0) {
            int n = n0 + (i >> 2) * 64 + ty * 4 + (i & 3);
            Vpart[((size_t)b * HW + n) * 8 + s] = v;
            Ipart[((size_t)b * HW + n) * 8 + s] = ix;
        }
    }
}

// ---------------------------------------------------------------------------
// Kernel 2b: combine the 8 m-split partials per (b,n). s ascending = m
// ascending, so >/== keeps first-occurrence.
// ---------------------------------------------------------------------------
__global__ __launch_bounds__(256) void reduce_kernel(
    const float* __restrict__ Vpart, const int* __restrict__ Ipart,
    int* __restrict__ IDX)
{
    const int i = blockIdx.x * 256 + threadIdx.x;   // b*HW + n, 16384 total
    float bv = -1e30f;
    int   bi = 0;
    #pragma unroll
    for (int s = 0; s < 8; ++s) {
        float v = Vpart[(size_t)i * 8 + s];
        int  ix = Ipart[(size_t)i * 8 + s];
        if (v > bv || (v == bv && ix < bi)) { bv = v; bi = ix; }
    }
    IDX[i] = bi;
}

// ---------------------------------------------------------------------------
// Kernel 3: gather.  out[b][c][n] = Fp[b][c][ IDX[b][n] ]
// ---------------------------------------------------------------------------
__global__ __launch_bounds__(256) void gather_kernel(
    const float* __restrict__ Fp, const int* __restrict__ IDX,
    float* __restrict__ out)
{
    const int i = blockIdx.x * 256 + threadIdx.x;   // 4*256*4096 total
    const int n = i & 4095;
    const int c = (i >> 12) & 255;
    const int b = i >> 20;
    const int idx = IDX[(b << 12) + n];
    out[i] = Fp[(size_t)((b << 8) + c) * HW + idx];
}

extern "C" void kernel_launch(void* const* d_in, const int* in_sizes, int n_in,
                              void* d_out, int out_size, void* d_ws, size_t ws_size,
                              hipStream_t stream) {
    const float* Fq   = (const float*)d_in[0];
    const float* Fp   = (const float*)d_in[1];
    const float* Wm   = (const float*)d_in[2];
    const float* bias = (const float*)d_in[3];
    float* out = (float*)d_out;

    // workspace layout:
    // Q [4*128*4096] f32 (8 MB) | P (8 MB) | Vpart [4*4096*8] f32 (512 KB)
    // | Ipart (512 KB) | IDX [4*4096] i32 (64 KB)   -> ~17.1 MB total
    float* Q     = (float*)d_ws;
    float* P     = Q + (size_t)4 * 128 * HW;
    float* Vpart = P + (size_t)4 * 128 * HW;
    int*   Ipart = (int*)(Vpart + (size_t)4 * HW * 8);
    int*   IDX   = Ipart + (size_t)4 * HW * 8;

    proj_kernel<<<dim3(64, 4, 2), 256, 0, stream>>>(Fq, Fp, Wm, bias, Q, P);
    simargmax_kernel<<<dim3(16, 4, 8), 256, 0, stream>>>(Q, P, Vpart, Ipart);
    reduce_kernel<<<64, 256, 0, stream>>>(Vpart, Ipart, IDX);
    gather_kernel<<<16384, 256, 0, stream>>>(Fp, IDX, out);
}